// Round 5
// baseline (568.061 us; speedup 1.0000x reference)
//
#include <hip/hip_runtime.h>
#include <math.h>

#define NN     96
#define EE     1024
#define HID    256
#define IND    64
#define ZD     64
#define NL     4656
#define NBLK   96
#define NTHR   384
#define ITERS  50
#define DSTEPS 25          // 2 MPM iterations per barrier
#define NBARS  33          // 7 encoder + 1 prologue + 25 double-steps
#define SHF    12544       // floats: Wd2 chunk (12544) / M(t) 9216 + X rows 3328
#define XOFF   9216        // X-row staging region inside SH
#define LISTCAP 1536

struct Params {
  const float* x; const int* ei; const float* adj;
  const float* W1; const float* b1; const float* g1; const float* be1;
  const float* W2; const float* b2; const float* g2; const float* be2;
  const float* Wmu; const float* bmu; const float* Wlv; const float* blv;
  const float* Wd1; const float* bd1; const float* Wd2; const float* bd2;
  const float* eps; float* out;
};

// All cross-block data behind agent-scope (sc1 / MALL-coherent) accesses;
// barriers need no cache writeback/invalidate.
__device__ float d_XW[NN*HID];
__device__ float d_H1pre[NN*HID];
__device__ float d_HW2[NN*HID];
__device__ float d_H2pre[NN*HID];
__device__ float d_mean1[HID], d_istd1[HID];
__device__ float d_gvec[HID];
__device__ float d_vec[NL];
__device__ float d_Xg[2][NN*NN];
__device__ float d_M[2][NN*NN];     // M[j][k] = max_l B[k,l]*X[j,l], published per row-owner
__device__ float d_ssq[DSTEPS+1];
// flag barrier: per-block monotonic epoch-flags (never reset; +NBARS per launch)
__device__ int   d_flag[NBLK];
__device__ int   d_epoch;

__device__ __forceinline__ float gld(const float* p) {
  return __hip_atomic_load(p, __ATOMIC_RELAXED, __HIP_MEMORY_SCOPE_AGENT);
}
__device__ __forceinline__ void gst(float* p, float v) {
  __hip_atomic_store(p, v, __ATOMIC_RELAXED, __HIP_MEMORY_SCOPE_AGENT);
}

__device__ __forceinline__ float wsum(float v) {
  v += __shfl_xor(v, 32, 64);
  v += __shfl_xor(v, 16, 64);
  v += __shfl_xor(v,  8, 64);
  v += __shfl_xor(v,  4, 64);
  v += __shfl_xor(v,  2, 64);
  v += __shfl_xor(v,  1, 64);
  return v;
}

__device__ __forceinline__ int tri_idx(int a, int c) {
  return a*95 - (a*(a-1))/2 + (c - a - 1);
}

// Fence-free grid barrier (proven in R4): drain own sc1 stores, block-sync,
// t0 publishes flag, 96 threads poll per-block flags, block-sync.
__device__ __forceinline__ void gbar(int idx, int base) {
  asm volatile("s_waitcnt vmcnt(0)" ::: "memory");
  __syncthreads();
  const int tgt = base + idx + 1;
  if (threadIdx.x == 0)
    __hip_atomic_store(&d_flag[blockIdx.x], tgt, __ATOMIC_RELAXED, __HIP_MEMORY_SCOPE_AGENT);
  if (threadIdx.x < NBLK) {
    while (__hip_atomic_load(&d_flag[threadIdx.x], __ATOMIC_RELAXED, __HIP_MEMORY_SCOPE_AGENT) < tgt)
      __builtin_amdgcn_s_sleep(2);
  }
  __syncthreads();
}

__global__ void __launch_bounds__(NTHR) gvae_kernel(Params p) {
  const int b = blockIdx.x;
  const int t = threadIdx.x;

  __shared__ __align__(16) float SH[SHF];   // 50.2 KB, serially reused
  __shared__ float pre1[HID];
  __shared__ float sg[HID], sd1[HID], sz[ZD];
  __shared__ float dinv[NN];
  __shared__ float eV[NN];   __shared__ int eL[NN];  __shared__ int s_ecnt;
  __shared__ float rowsq[NN], xb2[NN], sdegB[NN];
  __shared__ int   scnt[NN];
  __shared__ int   s_off[NN+1];
  __shared__ int   s_list[LISTCAP];
  __shared__ unsigned long long smask[NN][2];

  const int base = __hip_atomic_load(&d_epoch, __ATOMIC_RELAXED, __HIP_MEMORY_SCOPE_AGENT) * NBARS;

  //======== P0: build A (dense, dedup) -> dinv, encoder nbr list; XW row b; inits ========
  for (int i = t; i < NN*97; i += NTHR) SH[i] = 0.0f;
  __syncthreads();
  for (int e = t; e < EE; e += NTHR) {
    int s = p.ei[e], d = p.ei[EE + e];
    SH[s*97 + d] = 1.0f;                    // benign same-value LDS races
  }
  if (t < NN) SH[t*97 + t] = 1.0f;          // max(A, I)
  __syncthreads();
  if (t < NN) {
    float s = 0.0f;
    for (int j = 0; j < NN; ++j) s += SH[t*97 + j];
    dinv[t] = 1.0f / sqrtf(s);
  }
  if (t < 64) {                              // encoder nbr list of row b (incl self), ascending
    bool is1 = SH[b*97 + t] > 0.5f;
    unsigned long long m1 = __ballot(is1);
    if (is1) eL[__popcll(m1 & ((1ull << t) - 1))] = t;
    int c1 = __popcll(m1);
    bool is2 = (t < 32) && SH[b*97 + 64 + t] > 0.5f;
    unsigned long long m2 = __ballot(is2);
    if (is2) eL[c1 + __popcll(m2 & ((1ull << t) - 1))] = 64 + t;
    if (t == 0) s_ecnt = c1 + __popcll(m2);
  }
  __syncthreads();
  if (t < s_ecnt) eV[t] = dinv[b] * dinv[eL[t]];
  if (t < HID) {                             // XW row b = x[b,:] @ W1
    float acc = 0.0f;
    for (int d = 0; d < IND; ++d) acc += p.x[b*IND + d] * p.W1[d*HID + t];
    gst(&d_XW[b*HID + t], acc);
  }
  if (t < NN) gst(&d_Xg[0][b*NN + t], 1.0f/96.0f);
  if (b == 0 && t <= DSTEPS) gst(&d_ssq[t], (t == 0) ? 1.0f : 0.0f);
  gbar(0, base);

  //======== P1: H1pre row b = sum_nbr An[b,j]*XW[j,:] + b1 ========
  {
    const int lim = s_ecnt * HID;
    float tv[16];
    #pragma unroll
    for (int r = 0; r < 16; ++r) {
      int idx = t + r*NTHR;
      if (idx < lim) tv[r] = gld(&d_XW[eL[idx >> 8]*HID + (idx & 255)]);
    }
    #pragma unroll
    for (int r = 0; r < 16; ++r) {
      int idx = t + r*NTHR;
      if (idx < lim) SH[idx] = tv[r];
    }
    for (int idx = t + 16*NTHR; idx < lim; idx += NTHR)
      SH[idx] = gld(&d_XW[eL[idx >> 8]*HID + (idx & 255)]);
    __syncthreads();
    if (t < HID) {
      float acc = 0.0f;
      const int ec = s_ecnt;
      for (int n = 0; n < ec; ++n) acc += eV[n] * SH[n*HID + t];
      acc += p.b1[t];
      pre1[t] = acc;
      gst(&d_H1pre[b*HID + t], acc);
    }
  }
  gbar(1, base);

  //======== P2: BN1 stats — block b owns columns 3b..3b+2 ========
  if (b < 86) {
    int w = t >> 6, lane = t & 63;
    int c = b*3 + w;
    if (w < 3 && c < HID) {
      float v0 = gld(&d_H1pre[lane*HID + c]);
      float v1 = (lane < 32) ? gld(&d_H1pre[(64+lane)*HID + c]) : 0.0f;
      float mean = wsum(v0 + v1) * (1.0f/96.0f);
      float a0 = v0 - mean, a1 = (lane < 32) ? (v1 - mean) : 0.0f;
      float var = wsum(a0*a0 + a1*a1) * (1.0f/96.0f);
      if (lane == 0) { gst(&d_mean1[c], mean); gst(&d_istd1[c], 1.0f/sqrtf(var + 1e-5f)); }
    }
  }
  gbar(2, base);

  //======== P3: h1 row (local) -> HW2 row b = h1 @ W2 ========
  if (t < HID) {
    float m = gld(&d_mean1[t]), is = gld(&d_istd1[t]);
    pre1[t] = fmaxf((pre1[t] - m) * is * p.g1[t] + p.be1[t], 0.0f);
  }
  __syncthreads();
  if (t < HID) {
    float acc = 0.0f;
    for (int k = 0; k < HID; ++k) acc += pre1[k] * p.W2[k*HID + t];
    gst(&d_HW2[b*HID + t], acc);
  }
  gbar(3, base);

  //======== P4: H2pre row b = sum_nbr An[b,j]*HW2[j,:] + b2 ========
  {
    const int lim = s_ecnt * HID;
    float tv[16];
    #pragma unroll
    for (int r = 0; r < 16; ++r) {
      int idx = t + r*NTHR;
      if (idx < lim) tv[r] = gld(&d_HW2[eL[idx >> 8]*HID + (idx & 255)]);
    }
    #pragma unroll
    for (int r = 0; r < 16; ++r) {
      int idx = t + r*NTHR;
      if (idx < lim) SH[idx] = tv[r];
    }
    for (int idx = t + 16*NTHR; idx < lim; idx += NTHR)
      SH[idx] = gld(&d_HW2[eL[idx >> 8]*HID + (idx & 255)]);
    __syncthreads();
    if (t < HID) {
      float acc = 0.0f;
      const int ec = s_ecnt;
      for (int n = 0; n < ec; ++n) acc += eV[n] * SH[n*HID + t];
      acc += p.b2[t];
      gst(&d_H2pre[b*HID + t], acc);
    }
  }
  gbar(4, base);

  //======== P5: BN2 stats + gvec column — block b owns columns 3b..3b+2 ========
  if (b < 86) {
    int w = t >> 6, lane = t & 63;
    int c = b*3 + w;
    if (w < 3 && c < HID) {
      float v0 = gld(&d_H2pre[lane*HID + c]);
      float v1 = (lane < 32) ? gld(&d_H2pre[(64+lane)*HID + c]) : 0.0f;
      float mean = wsum(v0 + v1) * (1.0f/96.0f);
      float a0 = v0 - mean, a1 = (lane < 32) ? (v1 - mean) : 0.0f;
      float var = wsum(a0*a0 + a1*a1) * (1.0f/96.0f);
      float is = 1.0f / sqrtf(var + 1e-5f);
      float ga = p.g2[c], be = p.be2[c];
      float h0 = fmaxf((v0 - mean)*is*ga + be, 0.0f);
      float h1v = (lane < 32) ? fmaxf((v1 - mean)*is*ga + be, 0.0f) : 0.0f;
      float gs = wsum(h0 + h1v);
      if (lane == 0) gst(&d_gvec[c], gs * (1.0f/96.0f));
    }
  }
  gbar(5, base);

  //======== P6: z, d1 (block-local), vec chunk (49 outputs/block) ========
  if (t < HID) sg[t] = gld(&d_gvec[t]);
  __syncthreads();
  if (t < ZD) {
    float am = p.bmu[t], al = p.blv[t];
    for (int c = 0; c < HID; ++c) {
      float gv = sg[c];
      am += gv * p.Wmu[c*ZD + t];
      al += gv * p.Wlv[c*ZD + t];
    }
    al = fminf(fmaxf(al, -4.0f), 4.0f);
    sz[t] = am + p.eps[t] * expf(0.5f * al);
  }
  __syncthreads();
  if (t < HID) {
    float acc = p.bd1[t];
    for (int d = 0; d < ZD; ++d) acc += sz[d] * p.Wd1[d*HID + t];
    sd1[t] = fmaxf(acc, 0.0f);
  }
  __syncthreads();
  {
    const int o0 = b*49;
    const int nout = min(49, NL - o0);
    #pragma unroll 4
    for (int idx = t; idx < HID*49; idx += NTHR) {
      int k = idx / 49, o = idx - k*49;
      SH[idx] = (o0 + o < NL) ? p.Wd2[k*NL + o0 + o] : 0.0f;
    }
    __syncthreads();
    if (t < nout) {
      float acc = p.bd2[o0 + t];
      for (int k = 0; k < HID; ++k) acc += sd1[k] * SH[k*49 + t];
      gst(&d_vec[o0 + t], tanhf(acc));
    }
  }
  gbar(6, base);

  //======== MPM prologue: vec -> LDS; FULL adjacency lists; B row regs; degB; M(0) ========
  {
    float tv[13];
    #pragma unroll
    for (int r = 0; r < 13; ++r) {
      int idx = t + r*NTHR;
      if (idx < NL) tv[r] = gld(&d_vec[idx]);
    }
    #pragma unroll
    for (int r = 0; r < 13; ++r) {
      int idx = t + r*NTHR;
      if (idx < NL) SH[idx] = tv[r];
    }
  }
  // pass 1: per-node adjacency masks + counts (wave w handles nodes w*16..w*16+15)
  {
    const int w = t >> 6, lane = t & 63;
    #pragma unroll
    for (int i = 0; i < 16; ++i) {
      const int j = w*16 + i;
      float a1 = p.adj[j*NN + lane];
      float a2 = (lane < 32) ? p.adj[j*NN + 64 + lane] : 0.0f;
      unsigned long long m1 = __ballot(a1 > 0.5f);          // diag of adj_gt is 0
      unsigned long long m2 = __ballot((lane < 32) && (a2 > 0.5f));
      if (lane == 0) {
        smask[j][0] = m1; smask[j][1] = m2;
        scnt[j] = __popcll(m1) + __popcll(m2);
      }
    }
  }
  __syncthreads();
  if (t == 0) {
    int acc = 0;
    for (int j = 0; j < NN; ++j) { s_off[j] = acc; acc += scnt[j]; }
    s_off[NN] = acc;
  }
  __syncthreads();
  // pass 2: fill compressed lists (ascending)
  {
    const int w = t >> 6, lane = t & 63;
    #pragma unroll
    for (int i = 0; i < 16; ++i) {
      const int j = w*16 + i;
      unsigned long long m1 = smask[j][0], m2 = smask[j][1];
      if ((m1 >> lane) & 1)
        s_list[s_off[j] + __popcll(m1 & ((1ull << lane) - 1))] = lane;
      if (lane < 32 && ((m2 >> lane) & 1))
        s_list[s_off[j] + __popcll(m1) + __popcll(m2 & ((1ull << lane) - 1))] = 64 + lane;
    }
  }
  // B row kk in regs (diag zeroed = l!=k exclusion); degB[kk] to LDS
  const int kk = t >> 2;
  const int qq = t & 3;
  float breg[24];
  {
    float bs = 0.0f;
    const int lb = qq*24;
    #pragma unroll
    for (int s = 0; s < 24; ++s) {
      int l = lb + s;
      float v = 0.0f;
      if (l != kk) {
        int a  = kk < l ? kk : l;
        int cc = kk < l ? l : kk;
        v = 1.0f / (1.0f + expf(-SH[tri_idx(a, cc)]));
      }
      breg[s] = v;
      bs += v;
    }
    float tot = bs + __shfl_xor(bs, 1, 64);
    tot += __shfl_xor(tot, 2, 64);
    if (qq == 0) sdegB[kk] = tot + 1.0f;     // degB incl diag 1
  }
  // M(0) row b: X(0) uniform = 1/96
  {
    float vm = 0.0f;
    #pragma unroll
    for (int s = 0; s < 24; ++s) vm = fmaxf(vm, breg[s] * (1.0f/96.0f));
    vm = fmaxf(vm, __shfl_xor(vm, 1, 64));
    vm = fmaxf(vm, __shfl_xor(vm, 2, 64));
    if (qq == 0) gst(&d_M[0][b*NN + kk], vm);
  }
  gbar(7, base);

  //======== MPM: 25 double-steps (2 iterations per barrier) ========
  const int  myoff = s_off[b];
  const int  cnt   = s_off[b+1] - myoff;     // own neighbor count (slots 0..cnt-1; own row = slot cnt)
  const float dAb  = (float)(scnt[b] + 1);   // degA incl diag
  int cur = 0;
  for (int ds = 0; ds < DSTEPS; ++ds) {
    float s2 = gld(&d_ssq[ds]);
    int ex;
    (void)frexpf(sqrtf(s2), &ex);
    const float scale = ldexpf(1.0f, -ex);   // exact pow2 rescale (homogeneous map;
                                             // commutes bit-exactly with products)
    const float* Ms = d_M[cur];
    const float* Xs = d_Xg[cur];
    const int limX = (cnt + 1) * NN;
    // batched sc1 stage: ALL 96 M rows (9216) + X rows of S = nbr(b) u {b}
    {
      float tm[24], tx[8];
      #pragma unroll
      for (int r = 0; r < 24; ++r) tm[r] = gld(&Ms[t + r*NTHR]);   // 24*384 == 9216 exactly
      #pragma unroll
      for (int r = 0; r < 8; ++r) {
        int idx = t + r*NTHR;
        if (idx < limX) {
          int slot = idx / NN, col = idx - slot*NN;
          int j = (slot == cnt) ? b : s_list[myoff + slot];
          tx[r] = gld(&Xs[j*NN + col]);
        }
      }
      #pragma unroll
      for (int r = 0; r < 24; ++r) SH[t + r*NTHR] = tm[r] * scale;
      #pragma unroll
      for (int r = 0; r < 8; ++r) {
        int idx = t + r*NTHR;
        if (idx < limX) SH[XOFF + idx] = tx[r] * scale;
      }
      for (int idx = t + 8*NTHR; idx < limX; idx += NTHR) {        // deg > 31 fallback
        int slot = idx / NN, col = idx - slot*NN;
        int j = (slot == cnt) ? b : s_list[myoff + slot];
        SH[XOFF + idx] = gld(&Xs[j*NN + col]) * scale;
      }
    }
    __syncthreads();
    // X(t+1) in place for all slots (element-wise: safe in place, no cross-thread dep)
    for (int idx = t; idx < limX; idx += NTHR) {
      int slot = idx / NN, k = idx - slot*NN;
      int j = (slot == cnt) ? b : s_list[myoff + slot];
      float dAj = (float)(scnt[j] + 1);
      float es = 0.0f;
      const int o1 = s_off[j+1];
      for (int ptr = s_off[j]; ptr < o1; ++ptr)      // ascending m = reference order
        es += SH[s_list[ptr]*NN + k];
      SH[XOFF + idx] = SH[XOFF + idx] * (1.0f / (fabsf(dAj - sdegB[k]) + 1.0f)) + es;
    }
    __syncthreads();
    // M(t+1) for neighbor slots -> overlay on M(t) region (dead after previous phase)
    for (int s = 0; s < cnt; ++s) {
      const float4* xp = reinterpret_cast<const float4*>(&SH[XOFF + s*NN + qq*24]);
      float vm = 0.0f;
      #pragma unroll
      for (int s6 = 0; s6 < 6; ++s6) {
        float4 xv = xp[s6];
        vm = fmaxf(vm, breg[4*s6+0] * xv.x);
        vm = fmaxf(vm, breg[4*s6+1] * xv.y);
        vm = fmaxf(vm, breg[4*s6+2] * xv.z);
        vm = fmaxf(vm, breg[4*s6+3] * xv.w);
      }
      vm = fmaxf(vm, __shfl_xor(vm, 1, 64));
      vm = fmaxf(vm, __shfl_xor(vm, 2, 64));
      if (qq == 0) SH[s*NN + kk] = vm;
    }
    __syncthreads();
    // X(t+2) own row: edge sum (ascending j) then node term, publish + rowsq
    if (qq == 0) {
      float es = 0.0f;
      for (int s = 0; s < cnt; ++s) es += SH[s*NN + kk];
      float xn = SH[XOFF + cnt*NN + kk] * (1.0f / (fabsf(dAb - sdegB[kk]) + 1.0f)) + es;
      xb2[kk] = xn;
      rowsq[kk] = xn * xn;
      gst(&d_Xg[cur ^ 1][b*NN + kk], xn);
    }
    __syncthreads();
    // M(t+2) own row, publish; ssq contribution
    {
      const int lb = qq*24;
      float vm = 0.0f;
      #pragma unroll
      for (int s = 0; s < 24; ++s) vm = fmaxf(vm, breg[s] * xb2[lb + s]);
      vm = fmaxf(vm, __shfl_xor(vm, 1, 64));
      vm = fmaxf(vm, __shfl_xor(vm, 2, 64));
      if (qq == 0) gst(&d_M[cur ^ 1][b*NN + kk], vm);
    }
    if (t < 64) {
      float v = rowsq[t] + ((t < 32) ? rowsq[64 + t] : 0.0f);
      v = wsum(v);
      if (t == 0)
        __hip_atomic_fetch_add(&d_ssq[ds+1], v, __ATOMIC_RELAXED, __HIP_MEMORY_SCOPE_AGENT);
    }
    gbar(8 + ds, base);
    cur ^= 1;
  }

  //======== final true normalization (own row is local in xb2) ========
  if (t < NN) {
    float inv = 1.0f / sqrtf(gld(&d_ssq[DSTEPS]));
    p.out[b*NN + t] = xb2[t] * inv;
  }
  if (b == 0 && t == 0)
    __hip_atomic_fetch_add(&d_epoch, 1, __ATOMIC_RELAXED, __HIP_MEMORY_SCOPE_AGENT);
}

extern "C" void kernel_launch(void* const* d_in, const int* in_sizes, int n_in,
                              void* d_out, int out_size, void* d_ws, size_t ws_size,
                              hipStream_t stream) {
  Params prm;
  prm.x   = (const float*)d_in[0];
  prm.ei  = (const int*  )d_in[1];
  prm.adj = (const float*)d_in[2];
  prm.W1  = (const float*)d_in[3];
  prm.b1  = (const float*)d_in[4];
  prm.g1  = (const float*)d_in[5];
  prm.be1 = (const float*)d_in[6];
  prm.W2  = (const float*)d_in[7];
  prm.b2  = (const float*)d_in[8];
  prm.g2  = (const float*)d_in[9];
  prm.be2 = (const float*)d_in[10];
  prm.Wmu = (const float*)d_in[11];
  prm.bmu = (const float*)d_in[12];
  prm.Wlv = (const float*)d_in[13];
  prm.blv = (const float*)d_in[14];
  prm.Wd1 = (const float*)d_in[15];
  prm.bd1 = (const float*)d_in[16];
  prm.Wd2 = (const float*)d_in[17];
  prm.bd2 = (const float*)d_in[18];
  prm.eps = (const float*)d_in[19];
  prm.out = (float*)d_out;

  void* args[] = { &prm };
  hipLaunchCooperativeKernel(reinterpret_cast<void*>(&gvae_kernel),
                             dim3(NBLK), dim3(NTHR), args, 0, stream);
}

// Round 8
// 535.633 us; speedup vs baseline: 1.0605x; 1.0605x over previous
//
#include <hip/hip_runtime.h>
#include <math.h>

#define NN    96
#define EE    1024
#define HID   256
#define IND   64
#define ZD    64
#define NL    4656
#define NBLK  96
#define NTHR  384
#define ITERS 50
#define NBARS 57
#define SHF   (HID*49)     // 12544 floats: Wd2 chunk (largest user)

struct Params {
  const float* x; const int* ei; const float* adj;
  const float* W1; const float* b1; const float* g1; const float* be1;
  const float* W2; const float* b2; const float* g2; const float* be2;
  const float* Wmu; const float* bmu; const float* Wlv; const float* blv;
  const float* Wd1; const float* bd1; const float* Wd2; const float* bd2;
  const float* eps; float* out;
};

// All cross-block data behind agent-scope (sc1 / MALL-coherent) accesses;
// barriers need no cache writeback/invalidate.
__device__ float d_XW[NN*HID];
__device__ float d_H1pre[NN*HID];
__device__ float d_HW2[NN*HID];
__device__ float d_H2pre[NN*HID];
__device__ float d_mean1[HID], d_istd1[HID];
__device__ float d_gvec[HID];
__device__ float d_vec[NL];
__device__ float d_Xg[2][NN*NN];
__device__ float d_part[2][NN];     // per-block ||row||^2 partials, parity by iter
// two-stage barrier state (monotonic, never reset; +NBARS per launch)
__device__ int   d_flag[NBLK];      // arrival flags (blocks 1..95 write; block 0 scans)
__device__ int   d_rel;             // release word (block 0 writes; all others poll)
__device__ int   d_epoch;

__device__ __forceinline__ float gld(const float* p) {
  return __hip_atomic_load(p, __ATOMIC_RELAXED, __HIP_MEMORY_SCOPE_AGENT);
}
__device__ __forceinline__ void gst(float* p, float v) {
  __hip_atomic_store(p, v, __ATOMIC_RELAXED, __HIP_MEMORY_SCOPE_AGENT);
}

__device__ __forceinline__ float wsum(float v) {
  v += __shfl_xor(v, 32, 64);
  v += __shfl_xor(v, 16, 64);
  v += __shfl_xor(v,  8, 64);
  v += __shfl_xor(v,  4, 64);
  v += __shfl_xor(v,  2, 64);
  v += __shfl_xor(v,  1, 64);
  return v;
}

__device__ __forceinline__ int tri_idx(int a, int c) {
  return a*95 - (a*(a-1))/2 + (c - a - 1);
}

// Two-stage fence-free grid barrier. R5 showed the all-poll-all scheme
// congests one MALL slice (~9216 same-region loads/round). Here: arrivals are
// 95 parallel flag stores; ONE block scans them; everyone else polls a single
// release word with ONE thread. Poll traffic ~190 loads/round total.
__device__ __forceinline__ void gbar(int idx, int base) {
  asm volatile("s_waitcnt vmcnt(0)" ::: "memory");
  __syncthreads();
  const int tgt = base + idx + 1;
  const int t = threadIdx.x;
  if (blockIdx.x == 0) {
    if (t >= 1 && t < NBLK) {
      while (__hip_atomic_load(&d_flag[t], __ATOMIC_RELAXED, __HIP_MEMORY_SCOPE_AGENT) < tgt)
        __builtin_amdgcn_s_sleep(1);
    }
    __syncthreads();
    if (t == 0)
      __hip_atomic_store(&d_rel, tgt, __ATOMIC_RELAXED, __HIP_MEMORY_SCOPE_AGENT);
  } else {
    if (t == 0) {
      __hip_atomic_store(&d_flag[blockIdx.x], tgt, __ATOMIC_RELAXED, __HIP_MEMORY_SCOPE_AGENT);
      while (__hip_atomic_load(&d_rel, __ATOMIC_RELAXED, __HIP_MEMORY_SCOPE_AGENT) < tgt)
        __builtin_amdgcn_s_sleep(1);
    }
    __syncthreads();
  }
}

__global__ void __launch_bounds__(NTHR) gvae_kernel(Params p) {
  const int b = blockIdx.x;
  const int t = threadIdx.x;

  __shared__ __align__(16) float SH[SHF];   // 50.2 KB, serially reused
  __shared__ float pre1[HID];
  __shared__ float sg[HID], sd1[HID], sz[ZD];
  __shared__ float dinv[NN];
  __shared__ float eV[NN];   __shared__ int eL[NN];  __shared__ int s_ecnt;
  __shared__ float ndrow[NN], rowsq[NN], xb2[NN];
  __shared__ int   nbrL[NN];
  __shared__ float sdegA;    __shared__ int s_cnt;
  __shared__ float sF;

  const int base = __hip_atomic_load(&d_epoch, __ATOMIC_RELAXED, __HIP_MEMORY_SCOPE_AGENT) * NBARS;

  //======== P0: build A (dense, dedup) -> dinv, encoder nbr list; XW row b; inits ========
  for (int i = t; i < NN*97; i += NTHR) SH[i] = 0.0f;
  __syncthreads();
  for (int e = t; e < EE; e += NTHR) {
    int s = p.ei[e], d = p.ei[EE + e];
    SH[s*97 + d] = 1.0f;                    // benign same-value LDS races
  }
  if (t < NN) SH[t*97 + t] = 1.0f;          // max(A, I)
  __syncthreads();
  if (t < NN) {
    float s = 0.0f;
    for (int j = 0; j < NN; ++j) s += SH[t*97 + j];
    dinv[t] = 1.0f / sqrtf(s);
  }
  if (t < 64) {                              // encoder nbr list of row b (incl self), ascending
    bool is1 = SH[b*97 + t] > 0.5f;
    unsigned long long m1 = __ballot(is1);
    if (is1) eL[__popcll(m1 & ((1ull << t) - 1))] = t;
    int c1 = __popcll(m1);
    bool is2 = (t < 32) && SH[b*97 + 64 + t] > 0.5f;
    unsigned long long m2 = __ballot(is2);
    if (is2) eL[c1 + __popcll(m2 & ((1ull << t) - 1))] = 64 + t;
    if (t == 0) s_ecnt = c1 + __popcll(m2);
  }
  __syncthreads();
  if (t < s_ecnt) eV[t] = dinv[b] * dinv[eL[t]];
  if (t < HID) {                             // XW row b = x[b,:] @ W1
    float acc = 0.0f;
    for (int d = 0; d < IND; ++d) acc += p.x[b*IND + d] * p.W1[d*HID + t];
    gst(&d_XW[b*HID + t], acc);
  }
  if (t < NN) gst(&d_Xg[0][b*NN + t], 1.0f/96.0f);
  gbar(0, base);

  //======== P1: H1pre row b = sum_nbr An[b,j]*XW[j,:] + b1 ========
  {
    const int lim = s_ecnt * HID;
    float tv[16];
    #pragma unroll
    for (int r = 0; r < 16; ++r) {
      int idx = t + r*NTHR;
      if (idx < lim) tv[r] = gld(&d_XW[eL[idx >> 8]*HID + (idx & 255)]);
    }
    #pragma unroll
    for (int r = 0; r < 16; ++r) {
      int idx = t + r*NTHR;
      if (idx < lim) SH[idx] = tv[r];
    }
    for (int idx = t + 16*NTHR; idx < lim; idx += NTHR)
      SH[idx] = gld(&d_XW[eL[idx >> 8]*HID + (idx & 255)]);
    __syncthreads();
    if (t < HID) {
      float acc = 0.0f;
      const int ec = s_ecnt;
      for (int n = 0; n < ec; ++n) acc += eV[n] * SH[n*HID + t];
      acc += p.b1[t];
      pre1[t] = acc;
      gst(&d_H1pre[b*HID + t], acc);
    }
  }
  gbar(1, base);

  //======== P2: BN1 stats — block b owns columns 3b..3b+2 ========
  if (b < 86) {
    int w = t >> 6, lane = t & 63;
    int c = b*3 + w;
    if (w < 3 && c < HID) {
      float v0 = gld(&d_H1pre[lane*HID + c]);
      float v1 = (lane < 32) ? gld(&d_H1pre[(64+lane)*HID + c]) : 0.0f;
      float mean = wsum(v0 + v1) * (1.0f/96.0f);
      float a0 = v0 - mean, a1 = (lane < 32) ? (v1 - mean) : 0.0f;
      float var = wsum(a0*a0 + a1*a1) * (1.0f/96.0f);
      if (lane == 0) { gst(&d_mean1[c], mean); gst(&d_istd1[c], 1.0f/sqrtf(var + 1e-5f)); }
    }
  }
  gbar(2, base);

  //======== P3: h1 row (local) -> HW2 row b = h1 @ W2 ========
  if (t < HID) {
    float m = gld(&d_mean1[t]), is = gld(&d_istd1[t]);
    pre1[t] = fmaxf((pre1[t] - m) * is * p.g1[t] + p.be1[t], 0.0f);
  }
  __syncthreads();
  if (t < HID) {
    float acc = 0.0f;
    for (int k = 0; k < HID; ++k) acc += pre1[k] * p.W2[k*HID + t];
    gst(&d_HW2[b*HID + t], acc);
  }
  gbar(3, base);

  //======== P4: H2pre row b = sum_nbr An[b,j]*HW2[j,:] + b2 ========
  {
    const int lim = s_ecnt * HID;
    float tv[16];
    #pragma unroll
    for (int r = 0; r < 16; ++r) {
      int idx = t + r*NTHR;
      if (idx < lim) tv[r] = gld(&d_HW2[eL[idx >> 8]*HID + (idx & 255)]);
    }
    #pragma unroll
    for (int r = 0; r < 16; ++r) {
      int idx = t + r*NTHR;
      if (idx < lim) SH[idx] = tv[r];
    }
    for (int idx = t + 16*NTHR; idx < lim; idx += NTHR)
      SH[idx] = gld(&d_HW2[eL[idx >> 8]*HID + (idx & 255)]);
    __syncthreads();
    if (t < HID) {
      float acc = 0.0f;
      const int ec = s_ecnt;
      for (int n = 0; n < ec; ++n) acc += eV[n] * SH[n*HID + t];
      acc += p.b2[t];
      gst(&d_H2pre[b*HID + t], acc);
    }
  }
  gbar(4, base);

  //======== P5: BN2 stats + gvec column — block b owns columns 3b..3b+2 ========
  if (b < 86) {
    int w = t >> 6, lane = t & 63;
    int c = b*3 + w;
    if (w < 3 && c < HID) {
      float v0 = gld(&d_H2pre[lane*HID + c]);
      float v1 = (lane < 32) ? gld(&d_H2pre[(64+lane)*HID + c]) : 0.0f;
      float mean = wsum(v0 + v1) * (1.0f/96.0f);
      float a0 = v0 - mean, a1 = (lane < 32) ? (v1 - mean) : 0.0f;
      float var = wsum(a0*a0 + a1*a1) * (1.0f/96.0f);
      float is = 1.0f / sqrtf(var + 1e-5f);
      float ga = p.g2[c], be = p.be2[c];
      float h0 = fmaxf((v0 - mean)*is*ga + be, 0.0f);
      float h1v = (lane < 32) ? fmaxf((v1 - mean)*is*ga + be, 0.0f) : 0.0f;
      float gs = wsum(h0 + h1v);
      if (lane == 0) gst(&d_gvec[c], gs * (1.0f/96.0f));
    }
  }
  gbar(5, base);

  //======== P6: z, d1 (block-local), vec chunk (49 outputs/block) ========
  if (t < HID) sg[t] = gld(&d_gvec[t]);
  __syncthreads();
  if (t < ZD) {
    float am = p.bmu[t], al = p.blv[t];
    for (int c = 0; c < HID; ++c) {
      float gv = sg[c];
      am += gv * p.Wmu[c*ZD + t];
      al += gv * p.Wlv[c*ZD + t];
    }
    al = fminf(fmaxf(al, -4.0f), 4.0f);
    sz[t] = am + p.eps[t] * expf(0.5f * al);
  }
  __syncthreads();
  if (t < HID) {
    float acc = p.bd1[t];
    for (int d = 0; d < ZD; ++d) acc += sz[d] * p.Wd1[d*HID + t];
    sd1[t] = fmaxf(acc, 0.0f);
  }
  __syncthreads();
  {
    const int o0 = b*49;
    const int nout = min(49, NL - o0);
    #pragma unroll 4
    for (int idx = t; idx < HID*49; idx += NTHR) {
      int k = idx / 49, o = idx - k*49;
      SH[idx] = (o0 + o < NL) ? p.Wd2[k*NL + o0 + o] : 0.0f;
    }
    __syncthreads();
    if (t < nout) {
      float acc = p.bd2[o0 + t];
      for (int k = 0; k < HID; ++k) acc += sd1[k] * SH[k*49 + t];
      gst(&d_vec[o0 + t], tanhf(acc));
    }
  }
  gbar(6, base);

  //======== MPM prologue: stage vec -> LDS; adj nbr list; B row regs; ndrow ========
  {
    float tv[13];
    #pragma unroll
    for (int r = 0; r < 13; ++r) {
      int idx = t + r*NTHR;
      if (idx < NL) tv[r] = gld(&d_vec[idx]);
    }
    #pragma unroll
    for (int r = 0; r < 13; ++r) {
      int idx = t + r*NTHR;
      if (idx < NL) SH[idx] = tv[r];
    }
  }
  const int kk = t >> 2;
  const int qq = t & 3;
  if (t < 64) {
    float s = p.adj[b*NN + t] + ((t < 32) ? p.adj[b*NN + 64 + t] : 0.0f);
    s = wsum(s);
    if (t == 0) sdegA = s + 1.0f;
    bool is1 = (t != b) && (p.adj[b*NN + t] > 0.5f);
    unsigned long long m1 = __ballot(is1);
    if (is1) nbrL[__popcll(m1 & ((1ull << t) - 1))] = t;
    int c1 = __popcll(m1);
    bool is2 = (t < 32) && ((64 + t) != b) && (p.adj[b*NN + 64 + t] > 0.5f);
    unsigned long long m2 = __ballot(is2);
    if (is2) nbrL[c1 + __popcll(m2 & ((1ull << t) - 1))] = 64 + t;
    if (t == 0) s_cnt = c1 + __popcll(m2);
  }
  __syncthreads();

  float breg[24];
  {
    float bs = 0.0f;
    const int lb = qq*24;
    #pragma unroll
    for (int s = 0; s < 24; ++s) {
      int l = lb + s;
      float v = 0.0f;
      if (l != kk) {
        int a  = kk < l ? kk : l;
        int cc = kk < l ? l : kk;
        v = 1.0f / (1.0f + expf(-SH[tri_idx(a, cc)]));
      }
      breg[s] = v;
      bs += v;
    }
    float tot = bs + __shfl_xor(bs, 1, 64);
    tot += __shfl_xor(tot, 2, 64);
    if (qq == 0) ndrow[kk] = 1.0f / (fabsf(sdegA - (tot + 1.0f)) + 1.0f);
  }
  __syncthreads();     // all breg reads of SH done; SH free for X staging

  //======== MPM: 50 single steps; partial-based ssq; deferred pow2 scale ========
  int cur = 0;
  for (int it = 0; it < ITERS; ++it) {
    const int cnt = s_cnt;
    const int lim = (cnt + 1) * NN;
    const float* Xs = d_Xg[cur];
    // issue prev-iter partial loads AND X-row loads together (latencies overlap)
    float pj = 0.0f;
    if (it > 0 && t < NN) pj = gld(&d_part[(it-1) & 1][t]);
    float tv[8];
    #pragma unroll
    for (int r = 0; r < 8; ++r) {
      int idx = t + r*NTHR;
      if (idx < lim) {
        int slot = idx / NN, col = idx - slot*NN;
        int j = (slot == cnt) ? b : nbrL[slot];
        tv[r] = gld(&Xs[j*NN + col]);
      }
    }
    // redundant identical reduce of the 96 partials (same tree order in every
    // block -> bitwise-identical ssq -> consistent pow2 exponent everywhere)
    float s2 = 1.0f;                    // ||X0||^2 == 1 exactly
    if (it > 0) {
      if (t < NN) rowsq[t] = pj;
      __syncthreads();
      if (t < 64) {
        float v = rowsq[t] + ((t < 32) ? rowsq[64 + t] : 0.0f);
        v = wsum(v);
        if (t == 0) sF = v;
      }
      __syncthreads();
      s2 = sF;
    }
    int ex;
    (void)frexpf(sqrtf(s2), &ex);
    const float scale = ldexpf(1.0f, -ex);   // applied at the WRITE (pow2 scaling
                                             // commutes bit-exactly through mul/add/max)
    #pragma unroll
    for (int r = 0; r < 8; ++r) {
      int idx = t + r*NTHR;
      if (idx < lim) SH[idx] = tv[r];        // unscaled
    }
    for (int idx = t + 8*NTHR; idx < lim; idx += NTHR) {   // deg>31 fallback
      int slot = idx / NN, col = idx - slot*NN;
      int j = (slot == cnt) ? b : nbrL[slot];
      SH[idx] = gld(&Xs[j*NN + col]);
    }
    __syncthreads();

    float acc = 0.0f;
    for (int n = 0; n < cnt; ++n) {
      const float4* xp = reinterpret_cast<const float4*>(&SH[n*NN + qq*24]);
      float vm = 0.0f;
      #pragma unroll
      for (int s6 = 0; s6 < 6; ++s6) {
        float4 xv = xp[s6];
        vm = fmaxf(vm, breg[4*s6+0] * xv.x);
        vm = fmaxf(vm, breg[4*s6+1] * xv.y);
        vm = fmaxf(vm, breg[4*s6+2] * xv.z);
        vm = fmaxf(vm, breg[4*s6+3] * xv.w);
      }
      vm = fmaxf(vm, __shfl_xor(vm, 1, 64));
      vm = fmaxf(vm, __shfl_xor(vm, 2, 64));
      acc += vm;                               // ascending-j order = reference order
    }
    if (qq == 0) {
      float xn = scale * (SH[cnt*NN + kk] * ndrow[kk] + acc);
      xb2[kk] = xn;
      rowsq[kk] = xn * xn;
      gst(&d_Xg[cur ^ 1][b*NN + kk], xn);
    }
    __syncthreads();
    if (t < 64) {
      float v = rowsq[t] + ((t < 32) ? rowsq[64 + t] : 0.0f);
      v = wsum(v);
      if (t == 0) gst(&d_part[it & 1][b], v);  // parallel store, no RMW chain
    }
    gbar(7 + it, base);
    cur ^= 1;
  }

  //======== final normalization (identical redundant reduce; own row local) ========
  if (t < NN) rowsq[t] = gld(&d_part[(ITERS-1) & 1][t]);
  __syncthreads();
  if (t < 64) {
    float v = rowsq[t] + ((t < 32) ? rowsq[64 + t] : 0.0f);
    v = wsum(v);
    if (t == 0) sF = v;
  }
  __syncthreads();
  if (t < NN) p.out[b*NN + t] = xb2[t] * (1.0f / sqrtf(sF));

  if (b == 0 && t == 0)
    __hip_atomic_fetch_add(&d_epoch, 1, __ATOMIC_RELAXED, __HIP_MEMORY_SCOPE_AGENT);
}

extern "C" void kernel_launch(void* const* d_in, const int* in_sizes, int n_in,
                              void* d_out, int out_size, void* d_ws, size_t ws_size,
                              hipStream_t stream) {
  Params prm;
  prm.x   = (const float*)d_in[0];
  prm.ei  = (const int*  )d_in[1];
  prm.adj = (const float*)d_in[2];
  prm.W1  = (const float*)d_in[3];
  prm.b1  = (const float*)d_in[4];
  prm.g1  = (const float*)d_in[5];
  prm.be1 = (const float*)d_in[6];
  prm.W2  = (const float*)d_in[7];
  prm.b2  = (const float*)d_in[8];
  prm.g2  = (const float*)d_in[9];
  prm.be2 = (const float*)d_in[10];
  prm.Wmu = (const float*)d_in[11];
  prm.bmu = (const float*)d_in[12];
  prm.Wlv = (const float*)d_in[13];
  prm.blv = (const float*)d_in[14];
  prm.Wd1 = (const float*)d_in[15];
  prm.bd1 = (const float*)d_in[16];
  prm.Wd2 = (const float*)d_in[17];
  prm.bd2 = (const float*)d_in[18];
  prm.eps = (const float*)d_in[19];
  prm.out = (float*)d_out;

  void* args[] = { &prm };
  hipLaunchCooperativeKernel(reinterpret_cast<void*>(&gvae_kernel),
                             dim3(NBLK), dim3(NTHR), args, 0, stream);
}

// Round 9
// 459.055 us; speedup vs baseline: 1.2375x; 1.1668x over previous
//
#include <hip/hip_runtime.h>
#include <math.h>

#define NN    96
#define EE    1024
#define HID   256
#define IND   64
#define ZD    64
#define NL    4656
#define NBLK  96
#define NTHR  384
#define ITERS 50
#define NBARS 8            // 7 encoder + 1 final
#define SHF   (HID*49)     // 12544 floats: Wd2 chunk (largest user)

typedef unsigned long long ull;

struct Params {
  const float* x; const int* ei; const float* adj;
  const float* W1; const float* b1; const float* g1; const float* be1;
  const float* W2; const float* b2; const float* g2; const float* be2;
  const float* Wmu; const float* bmu; const float* Wlv; const float* blv;
  const float* Wd1; const float* bd1; const float* Wd2; const float* bd2;
  const float* eps; float* out;
};

// All cross-block data behind agent-scope (sc1 / MALL-coherent) accesses.
__device__ float d_XW[NN*HID];
__device__ float d_H1pre[NN*HID];
__device__ float d_HW2[NN*HID];
__device__ float d_H2pre[NN*HID];
__device__ float d_mean1[HID], d_istd1[HID];
__device__ float d_gvec[HID];
__device__ float d_vec[NL];
// MPM point-to-point state: published pow2-normalized rows + 64-bit progress
// flags (tag<<16 | E as signed 16-bit). tag = epoch*64 + it (monotone across
// launches). Parity-indexed; neighbor lag bounded by 1 iter => 2 buffers safe.
__device__ float d_P[2][NN*NN];
__device__ ull   d_prog[2][NN];
__device__ float d_rssq[NN];
// encoder two-stage barrier state (monotonic, never reset)
__device__ int   d_flag[NBLK];
__device__ int   d_rel;
__device__ int   d_epoch;

__device__ __forceinline__ float gld(const float* p) {
  return __hip_atomic_load(p, __ATOMIC_RELAXED, __HIP_MEMORY_SCOPE_AGENT);
}
__device__ __forceinline__ void gst(float* p, float v) {
  __hip_atomic_store(p, v, __ATOMIC_RELAXED, __HIP_MEMORY_SCOPE_AGENT);
}
__device__ __forceinline__ ull ldp(const ull* p) {
  return __hip_atomic_load(p, __ATOMIC_RELAXED, __HIP_MEMORY_SCOPE_AGENT);
}
__device__ __forceinline__ void stp(ull* p, ull v) {
  __hip_atomic_store(p, v, __ATOMIC_RELAXED, __HIP_MEMORY_SCOPE_AGENT);
}

__device__ __forceinline__ float wsum(float v) {
  v += __shfl_xor(v, 32, 64);
  v += __shfl_xor(v, 16, 64);
  v += __shfl_xor(v,  8, 64);
  v += __shfl_xor(v,  4, 64);
  v += __shfl_xor(v,  2, 64);
  v += __shfl_xor(v,  1, 64);
  return v;
}
__device__ __forceinline__ float wmax(float v) {
  v = fmaxf(v, __shfl_xor(v, 32, 64));
  v = fmaxf(v, __shfl_xor(v, 16, 64));
  v = fmaxf(v, __shfl_xor(v,  8, 64));
  v = fmaxf(v, __shfl_xor(v,  4, 64));
  v = fmaxf(v, __shfl_xor(v,  2, 64));
  v = fmaxf(v, __shfl_xor(v,  1, 64));
  return v;
}

__device__ __forceinline__ int tri_idx(int a, int c) {
  return a*95 - (a*(a-1))/2 + (c - a - 1);
}

// Two-stage fence-free grid barrier (encoder + final only).
__device__ __forceinline__ void gbar(int idx, int base) {
  asm volatile("s_waitcnt vmcnt(0)" ::: "memory");
  __syncthreads();
  const int tgt = base + idx + 1;
  const int t = threadIdx.x;
  if (blockIdx.x == 0) {
    if (t >= 1 && t < NBLK) {
      while (__hip_atomic_load(&d_flag[t], __ATOMIC_RELAXED, __HIP_MEMORY_SCOPE_AGENT) < tgt)
        __builtin_amdgcn_s_sleep(1);
    }
    __syncthreads();
    if (t == 0)
      __hip_atomic_store(&d_rel, tgt, __ATOMIC_RELAXED, __HIP_MEMORY_SCOPE_AGENT);
  } else {
    if (t == 0) {
      __hip_atomic_store(&d_flag[blockIdx.x], tgt, __ATOMIC_RELAXED, __HIP_MEMORY_SCOPE_AGENT);
      while (__hip_atomic_load(&d_rel, __ATOMIC_RELAXED, __HIP_MEMORY_SCOPE_AGENT) < tgt)
        __builtin_amdgcn_s_sleep(1);
    }
    __syncthreads();
  }
}

__global__ void __launch_bounds__(NTHR) gvae_kernel(Params p) {
  const int b = blockIdx.x;
  const int t = threadIdx.x;

  __shared__ __align__(16) float SH[SHF];   // 50.2 KB, serially reused
  __shared__ float pre1[HID];
  __shared__ float sg[HID], sd1[HID], sz[ZD];
  __shared__ float dinv[NN];
  __shared__ float eV[NN];   __shared__ int eL[NN];  __shared__ int s_ecnt;
  __shared__ float ndrow[NN], rowsq[NN], xb2[NN];
  __shared__ int   nbrL[NN];
  __shared__ int   s_dE[NN];                // per-slot exponent deltas / final E_j
  __shared__ float sdegA;    __shared__ int s_cnt;
  __shared__ float sF;       __shared__ int s_ei;  __shared__ int s_emax;

  const int epoch = __hip_atomic_load(&d_epoch, __ATOMIC_RELAXED, __HIP_MEMORY_SCOPE_AGENT);
  const int base  = epoch * NBARS;
  const ull ep64  = (ull)epoch * 64ull;     // iteration tag base (monotone across launches)

  //======== P0: build A (dense, dedup) -> dinv, encoder nbr list; XW row b ========
  for (int i = t; i < NN*97; i += NTHR) SH[i] = 0.0f;
  __syncthreads();
  for (int e = t; e < EE; e += NTHR) {
    int s = p.ei[e], d = p.ei[EE + e];
    SH[s*97 + d] = 1.0f;                    // benign same-value LDS races
  }
  if (t < NN) SH[t*97 + t] = 1.0f;          // max(A, I)
  __syncthreads();
  if (t < NN) {
    float s = 0.0f;
    for (int j = 0; j < NN; ++j) s += SH[t*97 + j];
    dinv[t] = 1.0f / sqrtf(s);
  }
  if (t < 64) {                              // encoder nbr list of row b (incl self), ascending
    bool is1 = SH[b*97 + t] > 0.5f;
    ull m1 = __ballot(is1);
    if (is1) eL[__popcll(m1 & ((1ull << t) - 1))] = t;
    int c1 = __popcll(m1);
    bool is2 = (t < 32) && SH[b*97 + 64 + t] > 0.5f;
    ull m2 = __ballot(is2);
    if (is2) eL[c1 + __popcll(m2 & ((1ull << t) - 1))] = 64 + t;
    if (t == 0) s_ecnt = c1 + __popcll(m2);
  }
  __syncthreads();
  if (t < s_ecnt) eV[t] = dinv[b] * dinv[eL[t]];
  if (t < HID) {                             // XW row b = x[b,:] @ W1
    float acc = 0.0f;
    for (int d = 0; d < IND; ++d) acc += p.x[b*IND + d] * p.W1[d*HID + t];
    gst(&d_XW[b*HID + t], acc);
  }
  gbar(0, base);

  //======== P1: H1pre row b = sum_nbr An[b,j]*XW[j,:] + b1 ========
  {
    const int lim = s_ecnt * HID;
    float tv[16];
    #pragma unroll
    for (int r = 0; r < 16; ++r) {
      int idx = t + r*NTHR;
      if (idx < lim) tv[r] = gld(&d_XW[eL[idx >> 8]*HID + (idx & 255)]);
    }
    #pragma unroll
    for (int r = 0; r < 16; ++r) {
      int idx = t + r*NTHR;
      if (idx < lim) SH[idx] = tv[r];
    }
    for (int idx = t + 16*NTHR; idx < lim; idx += NTHR)
      SH[idx] = gld(&d_XW[eL[idx >> 8]*HID + (idx & 255)]);
    __syncthreads();
    if (t < HID) {
      float acc = 0.0f;
      const int ec = s_ecnt;
      for (int n = 0; n < ec; ++n) acc += eV[n] * SH[n*HID + t];
      acc += p.b1[t];
      pre1[t] = acc;
      gst(&d_H1pre[b*HID + t], acc);
    }
  }
  gbar(1, base);

  //======== P2: BN1 stats — block b owns columns 3b..3b+2 ========
  if (b < 86) {
    int w = t >> 6, lane = t & 63;
    int c = b*3 + w;
    if (w < 3 && c < HID) {
      float v0 = gld(&d_H1pre[lane*HID + c]);
      float v1 = (lane < 32) ? gld(&d_H1pre[(64+lane)*HID + c]) : 0.0f;
      float mean = wsum(v0 + v1) * (1.0f/96.0f);
      float a0 = v0 - mean, a1 = (lane < 32) ? (v1 - mean) : 0.0f;
      float var = wsum(a0*a0 + a1*a1) * (1.0f/96.0f);
      if (lane == 0) { gst(&d_mean1[c], mean); gst(&d_istd1[c], 1.0f/sqrtf(var + 1e-5f)); }
    }
  }
  gbar(2, base);

  //======== P3: h1 row (local) -> HW2 row b = h1 @ W2 ========
  if (t < HID) {
    float m = gld(&d_mean1[t]), is = gld(&d_istd1[t]);
    pre1[t] = fmaxf((pre1[t] - m) * is * p.g1[t] + p.be1[t], 0.0f);
  }
  __syncthreads();
  if (t < HID) {
    float acc = 0.0f;
    for (int k = 0; k < HID; ++k) acc += pre1[k] * p.W2[k*HID + t];
    gst(&d_HW2[b*HID + t], acc);
  }
  gbar(3, base);

  //======== P4: H2pre row b = sum_nbr An[b,j]*HW2[j,:] + b2 ========
  {
    const int lim = s_ecnt * HID;
    float tv[16];
    #pragma unroll
    for (int r = 0; r < 16; ++r) {
      int idx = t + r*NTHR;
      if (idx < lim) tv[r] = gld(&d_HW2[eL[idx >> 8]*HID + (idx & 255)]);
    }
    #pragma unroll
    for (int r = 0; r < 16; ++r) {
      int idx = t + r*NTHR;
      if (idx < lim) SH[idx] = tv[r];
    }
    for (int idx = t + 16*NTHR; idx < lim; idx += NTHR)
      SH[idx] = gld(&d_HW2[eL[idx >> 8]*HID + (idx & 255)]);
    __syncthreads();
    if (t < HID) {
      float acc = 0.0f;
      const int ec = s_ecnt;
      for (int n = 0; n < ec; ++n) acc += eV[n] * SH[n*HID + t];
      acc += p.b2[t];
      gst(&d_H2pre[b*HID + t], acc);
    }
  }
  gbar(4, base);

  //======== P5: BN2 stats + gvec column — block b owns columns 3b..3b+2 ========
  if (b < 86) {
    int w = t >> 6, lane = t & 63;
    int c = b*3 + w;
    if (w < 3 && c < HID) {
      float v0 = gld(&d_H2pre[lane*HID + c]);
      float v1 = (lane < 32) ? gld(&d_H2pre[(64+lane)*HID + c]) : 0.0f;
      float mean = wsum(v0 + v1) * (1.0f/96.0f);
      float a0 = v0 - mean, a1 = (lane < 32) ? (v1 - mean) : 0.0f;
      float var = wsum(a0*a0 + a1*a1) * (1.0f/96.0f);
      float is = 1.0f / sqrtf(var + 1e-5f);
      float ga = p.g2[c], be = p.be2[c];
      float h0 = fmaxf((v0 - mean)*is*ga + be, 0.0f);
      float h1v = (lane < 32) ? fmaxf((v1 - mean)*is*ga + be, 0.0f) : 0.0f;
      float gs = wsum(h0 + h1v);
      if (lane == 0) gst(&d_gvec[c], gs * (1.0f/96.0f));
    }
  }
  gbar(5, base);

  //======== P6: z, d1 (block-local), vec chunk (49 outputs/block) ========
  if (t < HID) sg[t] = gld(&d_gvec[t]);
  __syncthreads();
  if (t < ZD) {
    float am = p.bmu[t], al = p.blv[t];
    for (int c = 0; c < HID; ++c) {
      float gv = sg[c];
      am += gv * p.Wmu[c*ZD + t];
      al += gv * p.Wlv[c*ZD + t];
    }
    al = fminf(fmaxf(al, -4.0f), 4.0f);
    sz[t] = am + p.eps[t] * expf(0.5f * al);
  }
  __syncthreads();
  if (t < HID) {
    float acc = p.bd1[t];
    for (int d = 0; d < ZD; ++d) acc += sz[d] * p.Wd1[d*HID + t];
    sd1[t] = fmaxf(acc, 0.0f);
  }
  __syncthreads();
  {
    const int o0 = b*49;
    const int nout = min(49, NL - o0);
    #pragma unroll 4
    for (int idx = t; idx < HID*49; idx += NTHR) {
      int k = idx / 49, o = idx - k*49;
      SH[idx] = (o0 + o < NL) ? p.Wd2[k*NL + o0 + o] : 0.0f;
    }
    __syncthreads();
    if (t < nout) {
      float acc = p.bd2[o0 + t];
      for (int k = 0; k < HID; ++k) acc += sd1[k] * SH[k*49 + t];
      gst(&d_vec[o0 + t], tanhf(acc));
    }
  }
  gbar(6, base);

  //======== MPM prologue: vec -> LDS; own adj nbr list; B row regs; ndrow ========
  {
    float tv[13];
    #pragma unroll
    for (int r = 0; r < 13; ++r) {
      int idx = t + r*NTHR;
      if (idx < NL) tv[r] = gld(&d_vec[idx]);
    }
    #pragma unroll
    for (int r = 0; r < 13; ++r) {
      int idx = t + r*NTHR;
      if (idx < NL) SH[idx] = tv[r];
    }
  }
  const int kk = t >> 2;
  const int qq = t & 3;
  if (t < 64) {
    float s = p.adj[b*NN + t] + ((t < 32) ? p.adj[b*NN + 64 + t] : 0.0f);
    s = wsum(s);
    if (t == 0) sdegA = s + 1.0f;
    bool is1 = (t != b) && (p.adj[b*NN + t] > 0.5f);
    ull m1 = __ballot(is1);
    if (is1) nbrL[__popcll(m1 & ((1ull << t) - 1))] = t;
    int c1 = __popcll(m1);
    bool is2 = (t < 32) && ((64 + t) != b) && (p.adj[b*NN + 64 + t] > 0.5f);
    ull m2 = __ballot(is2);
    if (is2) nbrL[c1 + __popcll(m2 & ((1ull << t) - 1))] = 64 + t;
    if (t == 0) s_cnt = c1 + __popcll(m2);
  }
  __syncthreads();

  float breg[24];
  {
    float bs = 0.0f;
    const int lb = qq*24;
    #pragma unroll
    for (int s = 0; s < 24; ++s) {
      int l = lb + s;
      float v = 0.0f;
      if (l != kk) {
        int a  = kk < l ? kk : l;
        int cc = kk < l ? l : kk;
        v = 1.0f / (1.0f + expf(-SH[tri_idx(a, cc)]));
      }
      breg[s] = v;
      bs += v;
    }
    float tot = bs + __shfl_xor(bs, 1, 64);
    tot += __shfl_xor(tot, 2, 64);
    if (qq == 0) ndrow[kk] = 1.0f / (fabsf(sdegA - (tot + 1.0f)) + 1.0f);
  }
  __syncthreads();     // breg reads of SH done; SH free for X staging

  //======== MPM: point-to-point, NO global barriers ========
  // Invariant: published P_b(it) = T_b(it) * 2^-E_b(it) (max in [1,2)); all
  // pow2 scalings are mantissa-exact. d_prog[it&1][b] = (ep64+it)<<16 | E&0xFFFF
  // (atomic (tag,E) snapshot). Neighbor lag <=1 iter -> parity buffers safe.
  const int cnt = s_cnt;
  int E_own = 0;

  // ---- iteration 1: X(0) = 1/96 uniform, no staging needed ----
  {
    float vm = 0.0f;
    #pragma unroll
    for (int s = 0; s < 24; ++s) vm = fmaxf(vm, breg[s] * (1.0f/96.0f));
    vm = fmaxf(vm, __shfl_xor(vm, 1, 64));
    vm = fmaxf(vm, __shfl_xor(vm, 2, 64));    // m0[kk], identical for every j
    float acc = 0.0f;
    for (int n = 0; n < cnt; ++n) acc += vm;  // ascending-j order, identical terms
    if (qq == 0) xb2[kk] = (1.0f/96.0f) * ndrow[kk] + acc;
  }
  __syncthreads();
  if (t < 64) {
    float m = xb2[t];
    if (t < 32) m = fmaxf(m, xb2[64 + t]);
    m = wmax(m);
    if (t == 0) s_ei = ilogbf(m);
  }
  __syncthreads();
  E_own += s_ei;
  if (qq == 0) {
    float Pv = ldexpf(xb2[kk], -s_ei);
    xb2[kk] = Pv;
    gst(&d_P[1][b*NN + kk], Pv);
  }
  asm volatile("s_waitcnt vmcnt(0)" ::: "memory");
  __syncthreads();
  if (t == 0) stp(&d_prog[1][b], ((ep64 + 1ull) << 16) | (ull)(E_own & 0xFFFF));

  // ---- iterations 2..50 ----
  for (int it = 2; it <= ITERS; ++it) {
    const int pb = (it - 1) & 1;
    // poll neighbor flags (one thread per neighbor, distinct addresses)
    if (t < cnt) {
      const int j = nbrL[t];
      const ull want = ep64 + (ull)(it - 1);
      ull f;
      while (((f = ldp(&d_prog[pb][j])) >> 16) < want)
        __builtin_amdgcn_s_sleep(1);
      s_dE[t] = (int)(short)(f & 0xFFFF) - E_own;   // exact pow2 adjust to b-units
    }
    __syncthreads();
    // stage neighbor rows, rescaled into b-units (ldexpf = exact)
    const int lim = cnt * NN;
    {
      float tv[8]; int te[8];
      #pragma unroll
      for (int r = 0; r < 8; ++r) {
        int idx = t + r*NTHR;
        if (idx < lim) {
          int slot = idx / NN, col = idx - slot*NN;
          tv[r] = gld(&d_P[pb][nbrL[slot]*NN + col]);
          te[r] = s_dE[slot];
        }
      }
      #pragma unroll
      for (int r = 0; r < 8; ++r) {
        int idx = t + r*NTHR;
        if (idx < lim) SH[idx] = ldexpf(tv[r], te[r]);
      }
      for (int idx = t + 8*NTHR; idx < lim; idx += NTHR) {   // deg>31 fallback
        int slot = idx / NN, col = idx - slot*NN;
        SH[idx] = ldexpf(gld(&d_P[pb][nbrL[slot]*NN + col]), s_dE[slot]);
      }
    }
    __syncthreads();
    // compute own row (ascending-j order = reference order)
    float acc = 0.0f;
    for (int n = 0; n < cnt; ++n) {
      const float4* xp = reinterpret_cast<const float4*>(&SH[n*NN + qq*24]);
      float vm = 0.0f;
      #pragma unroll
      for (int s6 = 0; s6 < 6; ++s6) {
        float4 xv = xp[s6];
        vm = fmaxf(vm, breg[4*s6+0] * xv.x);
        vm = fmaxf(vm, breg[4*s6+1] * xv.y);
        vm = fmaxf(vm, breg[4*s6+2] * xv.z);
        vm = fmaxf(vm, breg[4*s6+3] * xv.w);
      }
      vm = fmaxf(vm, __shfl_xor(vm, 1, 64));
      vm = fmaxf(vm, __shfl_xor(vm, 2, 64));
      acc += vm;
    }
    if (qq == 0) xb2[kk] = xb2[kk] * ndrow[kk] + acc;   // own term uses P_own (b-units)
    __syncthreads();
    // pow2 renormalize: e = ilogb(rowmax); publish P = row * 2^-e
    if (t < 64) {
      float m = xb2[t];
      if (t < 32) m = fmaxf(m, xb2[64 + t]);
      m = wmax(m);
      if (t == 0) s_ei = ilogbf(m);
    }
    __syncthreads();
    E_own += s_ei;
    if (qq == 0) {
      float Pv = ldexpf(xb2[kk], -s_ei);
      xb2[kk] = Pv;
      gst(&d_P[it & 1][b*NN + kk], Pv);
    }
    asm volatile("s_waitcnt vmcnt(0)" ::: "memory");
    __syncthreads();
    if (t == 0) stp(&d_prog[it & 1][b], ((ep64 + (ull)it) << 16) | (ull)(E_own & 0xFFFF));
  }

  //======== final: publish row ssq; one global barrier; exponent-aware normalize ========
  if (t < NN) rowsq[t] = xb2[t] * xb2[t];
  __syncthreads();
  if (t < 64) {
    float v = rowsq[t] + ((t < 32) ? rowsq[64 + t] : 0.0f);
    v = wsum(v);
    if (t == 0) gst(&d_rssq[b], v);
  }
  gbar(7, base);
  // every block reads all 96 (ssq_j, E_j); identical order -> identical result
  if (t < NN) {
    ull f = ldp(&d_prog[ITERS & 1][t]);       // tag exactly ep64+50; E in low bits
    s_dE[t] = (int)(short)(f & 0xFFFF);
    rowsq[t] = gld(&d_rssq[t]);
  }
  __syncthreads();
  if (t == 0) {
    int em = s_dE[0];
    for (int j = 1; j < NN; ++j) em = max(em, s_dE[j]);
    float s = 0.0f;
    for (int j = 0; j < NN; ++j) s += ldexpf(rowsq[j], 2*(s_dE[j] - em));
    s_emax = em;
    sF = 1.0f / sqrtf(s);
  }
  __syncthreads();
  if (t < NN) p.out[b*NN + t] = ldexpf(xb2[t] * sF, E_own - s_emax);

  if (b == 0 && t == 0)
    __hip_atomic_fetch_add(&d_epoch, 1, __ATOMIC_RELAXED, __HIP_MEMORY_SCOPE_AGENT);
}

extern "C" void kernel_launch(void* const* d_in, const int* in_sizes, int n_in,
                              void* d_out, int out_size, void* d_ws, size_t ws_size,
                              hipStream_t stream) {
  Params prm;
  prm.x   = (const float*)d_in[0];
  prm.ei  = (const int*  )d_in[1];
  prm.adj = (const float*)d_in[2];
  prm.W1  = (const float*)d_in[3];
  prm.b1  = (const float*)d_in[4];
  prm.g1  = (const float*)d_in[5];
  prm.be1 = (const float*)d_in[6];
  prm.W2  = (const float*)d_in[7];
  prm.b2  = (const float*)d_in[8];
  prm.g2  = (const float*)d_in[9];
  prm.be2 = (const float*)d_in[10];
  prm.Wmu = (const float*)d_in[11];
  prm.bmu = (const float*)d_in[12];
  prm.Wlv = (const float*)d_in[13];
  prm.blv = (const float*)d_in[14];
  prm.Wd1 = (const float*)d_in[15];
  prm.bd1 = (const float*)d_in[16];
  prm.Wd2 = (const float*)d_in[17];
  prm.bd2 = (const float*)d_in[18];
  prm.eps = (const float*)d_in[19];
  prm.out = (float*)d_out;

  // Regular launch: all sync is custom flag-based; 96 blocks <= 256 CUs are
  // co-resident. Avoids cooperative-launch overhead (~115us wall-kernel gap).
  gvae_kernel<<<dim3(NBLK), dim3(NTHR), 0, stream>>>(prm);
}

// Round 10
// 449.183 us; speedup vs baseline: 1.2647x; 1.0220x over previous
//
#include <hip/hip_runtime.h>
#include <math.h>

#define NN    96
#define EE    1024
#define HID   256
#define IND   64
#define ZD    64
#define NL    4656
#define NBLK  96
#define NTHR  384
#define ITERS 50
#define NBARS 8            // 7 encoder + 1 final
#define SHF   (HID*49)     // 12544 floats: Wd2 chunk (largest user)

typedef unsigned long long ull;

struct Params {
  const float* x; const int* ei; const float* adj;
  const float* W1; const float* b1; const float* g1; const float* be1;
  const float* W2; const float* b2; const float* g2; const float* be2;
  const float* Wmu; const float* bmu; const float* Wlv; const float* blv;
  const float* Wd1; const float* bd1; const float* Wd2; const float* bd2;
  const float* eps; float* out;
};

// All cross-block data behind agent-scope (sc1 / MALL-coherent) accesses.
__device__ float d_XW[NN*HID];
__device__ float d_H1pre[NN*HID];
__device__ float d_HW2[NN*HID];
__device__ float d_H2pre[NN*HID];
__device__ float d_mean1[HID], d_istd1[HID];
__device__ float d_gvec[HID];
__device__ float d_vec[NL];
// MPM p2p state: per-element tagged pairs. .x = (tag32<<32)|E32(signed),
// .y = (tag32<<32)|f32bits. tag = epoch*64+it (monotone across launches) =>
// stale words self-invalidate; no flags, no publisher drain. Parity buffers;
// neighbor lag <=1 iter (j can't write it+2 into this parity slot until b
// published it+1, which happens-after b consumed j's it words).
__device__ ulonglong2 d_Pw[2][NN*NN];
__device__ float d_rssq[NN];
// encoder two-stage barrier state (monotonic, never reset)
__device__ int   d_flag[NBLK];
__device__ int   d_rel;
__device__ int   d_epoch;

__device__ __forceinline__ float gld(const float* p) {
  return __hip_atomic_load(p, __ATOMIC_RELAXED, __HIP_MEMORY_SCOPE_AGENT);
}
__device__ __forceinline__ void gst(float* p, float v) {
  __hip_atomic_store(p, v, __ATOMIC_RELAXED, __HIP_MEMORY_SCOPE_AGENT);
}
__device__ __forceinline__ ull ldp(const ull* p) {
  return __hip_atomic_load(p, __ATOMIC_RELAXED, __HIP_MEMORY_SCOPE_AGENT);
}
__device__ __forceinline__ void stp(ull* p, ull v) {
  __hip_atomic_store(p, v, __ATOMIC_RELAXED, __HIP_MEMORY_SCOPE_AGENT);
}

__device__ __forceinline__ float wsum(float v) {
  v += __shfl_xor(v, 32, 64);
  v += __shfl_xor(v, 16, 64);
  v += __shfl_xor(v,  8, 64);
  v += __shfl_xor(v,  4, 64);
  v += __shfl_xor(v,  2, 64);
  v += __shfl_xor(v,  1, 64);
  return v;
}
__device__ __forceinline__ float wmax(float v) {
  v = fmaxf(v, __shfl_xor(v, 32, 64));
  v = fmaxf(v, __shfl_xor(v, 16, 64));
  v = fmaxf(v, __shfl_xor(v,  8, 64));
  v = fmaxf(v, __shfl_xor(v,  4, 64));
  v = fmaxf(v, __shfl_xor(v,  2, 64));
  v = fmaxf(v, __shfl_xor(v,  1, 64));
  return v;
}

__device__ __forceinline__ int tri_idx(int a, int c) {
  return a*95 - (a*(a-1))/2 + (c - a - 1);
}

// Two-stage fence-free grid barrier (encoder + final only).
__device__ __forceinline__ void gbar(int idx, int base) {
  asm volatile("s_waitcnt vmcnt(0)" ::: "memory");
  __syncthreads();
  const int tgt = base + idx + 1;
  const int t = threadIdx.x;
  if (blockIdx.x == 0) {
    if (t >= 1 && t < NBLK) {
      while (__hip_atomic_load(&d_flag[t], __ATOMIC_RELAXED, __HIP_MEMORY_SCOPE_AGENT) < tgt)
        __builtin_amdgcn_s_sleep(1);
    }
    __syncthreads();
    if (t == 0)
      __hip_atomic_store(&d_rel, tgt, __ATOMIC_RELAXED, __HIP_MEMORY_SCOPE_AGENT);
  } else {
    if (t == 0) {
      __hip_atomic_store(&d_flag[blockIdx.x], tgt, __ATOMIC_RELAXED, __HIP_MEMORY_SCOPE_AGENT);
      while (__hip_atomic_load(&d_rel, __ATOMIC_RELAXED, __HIP_MEMORY_SCOPE_AGENT) < tgt)
        __builtin_amdgcn_s_sleep(1);
    }
    __syncthreads();
  }
}

__global__ void __launch_bounds__(NTHR) gvae_kernel(Params p) {
  const int b = blockIdx.x;
  const int t = threadIdx.x;

  __shared__ __align__(16) float SH[SHF];   // 50.2 KB, serially reused
  __shared__ float pre1[HID];
  __shared__ float sg[HID], sd1[HID], sz[ZD];
  __shared__ float dinv[NN];
  __shared__ float eV[NN];   __shared__ int eL[NN];  __shared__ int s_ecnt;
  __shared__ float ndrow[NN], rowsq[NN], xb2[NN];
  __shared__ int   nbrL[NN];
  __shared__ int   s_dE[NN];
  __shared__ float sdegA;    __shared__ int s_cnt;
  __shared__ float sF;       __shared__ int s_ei;  __shared__ int s_emax;

  const int epoch = __hip_atomic_load(&d_epoch, __ATOMIC_RELAXED, __HIP_MEMORY_SCOPE_AGENT);
  const int base  = epoch * NBARS;
  const ull ep64  = (ull)epoch * 64ull;     // iteration tag base (monotone across launches)

  //======== P0: build A (dense, dedup) -> dinv, encoder nbr list; XW row b ========
  for (int i = t; i < NN*97; i += NTHR) SH[i] = 0.0f;
  __syncthreads();
  for (int e = t; e < EE; e += NTHR) {
    int s = p.ei[e], d = p.ei[EE + e];
    SH[s*97 + d] = 1.0f;                    // benign same-value LDS races
  }
  if (t < NN) SH[t*97 + t] = 1.0f;          // max(A, I)
  __syncthreads();
  if (t < NN) {
    float s = 0.0f;
    for (int j = 0; j < NN; ++j) s += SH[t*97 + j];
    dinv[t] = 1.0f / sqrtf(s);
  }
  if (t < 64) {                              // encoder nbr list of row b (incl self), ascending
    bool is1 = SH[b*97 + t] > 0.5f;
    ull m1 = __ballot(is1);
    if (is1) eL[__popcll(m1 & ((1ull << t) - 1))] = t;
    int c1 = __popcll(m1);
    bool is2 = (t < 32) && SH[b*97 + 64 + t] > 0.5f;
    ull m2 = __ballot(is2);
    if (is2) eL[c1 + __popcll(m2 & ((1ull << t) - 1))] = 64 + t;
    if (t == 0) s_ecnt = c1 + __popcll(m2);
  }
  __syncthreads();
  if (t < s_ecnt) eV[t] = dinv[b] * dinv[eL[t]];
  if (t < HID) {                             // XW row b = x[b,:] @ W1
    float acc = 0.0f;
    for (int d = 0; d < IND; ++d) acc += p.x[b*IND + d] * p.W1[d*HID + t];
    gst(&d_XW[b*HID + t], acc);
  }
  gbar(0, base);

  //======== P1: H1pre row b = sum_nbr An[b,j]*XW[j,:] + b1 ========
  {
    const int lim = s_ecnt * HID;
    float tv[16];
    #pragma unroll
    for (int r = 0; r < 16; ++r) {
      int idx = t + r*NTHR;
      if (idx < lim) tv[r] = gld(&d_XW[eL[idx >> 8]*HID + (idx & 255)]);
    }
    #pragma unroll
    for (int r = 0; r < 16; ++r) {
      int idx = t + r*NTHR;
      if (idx < lim) SH[idx] = tv[r];
    }
    for (int idx = t + 16*NTHR; idx < lim; idx += NTHR)
      SH[idx] = gld(&d_XW[eL[idx >> 8]*HID + (idx & 255)]);
    __syncthreads();
    if (t < HID) {
      float acc = 0.0f;
      const int ec = s_ecnt;
      for (int n = 0; n < ec; ++n) acc += eV[n] * SH[n*HID + t];
      acc += p.b1[t];
      pre1[t] = acc;
      gst(&d_H1pre[b*HID + t], acc);
    }
  }
  gbar(1, base);

  //======== P2: BN1 stats — block b owns columns 3b..3b+2 ========
  if (b < 86) {
    int w = t >> 6, lane = t & 63;
    int c = b*3 + w;
    if (w < 3 && c < HID) {
      float v0 = gld(&d_H1pre[lane*HID + c]);
      float v1 = (lane < 32) ? gld(&d_H1pre[(64+lane)*HID + c]) : 0.0f;
      float mean = wsum(v0 + v1) * (1.0f/96.0f);
      float a0 = v0 - mean, a1 = (lane < 32) ? (v1 - mean) : 0.0f;
      float var = wsum(a0*a0 + a1*a1) * (1.0f/96.0f);
      if (lane == 0) { gst(&d_mean1[c], mean); gst(&d_istd1[c], 1.0f/sqrtf(var + 1e-5f)); }
    }
  }
  gbar(2, base);

  //======== P3: h1 row (local) -> HW2 row b = h1 @ W2 ========
  if (t < HID) {
    float m = gld(&d_mean1[t]), is = gld(&d_istd1[t]);
    pre1[t] = fmaxf((pre1[t] - m) * is * p.g1[t] + p.be1[t], 0.0f);
  }
  __syncthreads();
  if (t < HID) {
    float acc = 0.0f;
    for (int k = 0; k < HID; ++k) acc += pre1[k] * p.W2[k*HID + t];
    gst(&d_HW2[b*HID + t], acc);
  }
  gbar(3, base);

  //======== P4: H2pre row b = sum_nbr An[b,j]*HW2[j,:] + b2 ========
  {
    const int lim = s_ecnt * HID;
    float tv[16];
    #pragma unroll
    for (int r = 0; r < 16; ++r) {
      int idx = t + r*NTHR;
      if (idx < lim) tv[r] = gld(&d_HW2[eL[idx >> 8]*HID + (idx & 255)]);
    }
    #pragma unroll
    for (int r = 0; r < 16; ++r) {
      int idx = t + r*NTHR;
      if (idx < lim) SH[idx] = tv[r];
    }
    for (int idx = t + 16*NTHR; idx < lim; idx += NTHR)
      SH[idx] = gld(&d_HW2[eL[idx >> 8]*HID + (idx & 255)]);
    __syncthreads();
    if (t < HID) {
      float acc = 0.0f;
      const int ec = s_ecnt;
      for (int n = 0; n < ec; ++n) acc += eV[n] * SH[n*HID + t];
      acc += p.b2[t];
      gst(&d_H2pre[b*HID + t], acc);
    }
  }
  gbar(4, base);

  //======== P5: BN2 stats + gvec column — block b owns columns 3b..3b+2 ========
  if (b < 86) {
    int w = t >> 6, lane = t & 63;
    int c = b*3 + w;
    if (w < 3 && c < HID) {
      float v0 = gld(&d_H2pre[lane*HID + c]);
      float v1 = (lane < 32) ? gld(&d_H2pre[(64+lane)*HID + c]) : 0.0f;
      float mean = wsum(v0 + v1) * (1.0f/96.0f);
      float a0 = v0 - mean, a1 = (lane < 32) ? (v1 - mean) : 0.0f;
      float var = wsum(a0*a0 + a1*a1) * (1.0f/96.0f);
      float is = 1.0f / sqrtf(var + 1e-5f);
      float ga = p.g2[c], be = p.be2[c];
      float h0 = fmaxf((v0 - mean)*is*ga + be, 0.0f);
      float h1v = (lane < 32) ? fmaxf((v1 - mean)*is*ga + be, 0.0f) : 0.0f;
      float gs = wsum(h0 + h1v);
      if (lane == 0) gst(&d_gvec[c], gs * (1.0f/96.0f));
    }
  }
  gbar(5, base);

  //======== P6: z, d1 (block-local), vec chunk (49 outputs/block) ========
  if (t < HID) sg[t] = gld(&d_gvec[t]);
  __syncthreads();
  if (t < ZD) {
    float am = p.bmu[t], al = p.blv[t];
    for (int c = 0; c < HID; ++c) {
      float gv = sg[c];
      am += gv * p.Wmu[c*ZD + t];
      al += gv * p.Wlv[c*ZD + t];
    }
    al = fminf(fmaxf(al, -4.0f), 4.0f);
    sz[t] = am + p.eps[t] * expf(0.5f * al);
  }
  __syncthreads();
  if (t < HID) {
    float acc = p.bd1[t];
    for (int d = 0; d < ZD; ++d) acc += sz[d] * p.Wd1[d*HID + t];
    sd1[t] = fmaxf(acc, 0.0f);
  }
  __syncthreads();
  {
    const int o0 = b*49;
    const int nout = min(49, NL - o0);
    #pragma unroll 4
    for (int idx = t; idx < HID*49; idx += NTHR) {
      int k = idx / 49, o = idx - k*49;
      SH[idx] = (o0 + o < NL) ? p.Wd2[k*NL + o0 + o] : 0.0f;
    }
    __syncthreads();
    if (t < nout) {
      float acc = p.bd2[o0 + t];
      for (int k = 0; k < HID; ++k) acc += sd1[k] * SH[k*49 + t];
      gst(&d_vec[o0 + t], tanhf(acc));
    }
  }
  gbar(6, base);

  //======== MPM prologue: vec -> LDS; own adj nbr list; B row regs; ndrow ========
  {
    float tv[13];
    #pragma unroll
    for (int r = 0; r < 13; ++r) {
      int idx = t + r*NTHR;
      if (idx < NL) tv[r] = gld(&d_vec[idx]);
    }
    #pragma unroll
    for (int r = 0; r < 13; ++r) {
      int idx = t + r*NTHR;
      if (idx < NL) SH[idx] = tv[r];
    }
  }
  const int kk = t >> 2;
  const int qq = t & 3;
  if (t < 64) {
    float s = p.adj[b*NN + t] + ((t < 32) ? p.adj[b*NN + 64 + t] : 0.0f);
    s = wsum(s);
    if (t == 0) sdegA = s + 1.0f;
    bool is1 = (t != b) && (p.adj[b*NN + t] > 0.5f);
    ull m1 = __ballot(is1);
    if (is1) nbrL[__popcll(m1 & ((1ull << t) - 1))] = t;
    int c1 = __popcll(m1);
    bool is2 = (t < 32) && ((64 + t) != b) && (p.adj[b*NN + 64 + t] > 0.5f);
    ull m2 = __ballot(is2);
    if (is2) nbrL[c1 + __popcll(m2 & ((1ull << t) - 1))] = 64 + t;
    if (t == 0) s_cnt = c1 + __popcll(m2);
  }
  __syncthreads();

  float breg[24];
  {
    float bs = 0.0f;
    const int lb = qq*24;
    #pragma unroll
    for (int s = 0; s < 24; ++s) {
      int l = lb + s;
      float v = 0.0f;
      if (l != kk) {
        int a  = kk < l ? kk : l;
        int cc = kk < l ? l : kk;
        v = 1.0f / (1.0f + expf(-SH[tri_idx(a, cc)]));
      }
      breg[s] = v;
      bs += v;
    }
    float tot = bs + __shfl_xor(bs, 1, 64);
    tot += __shfl_xor(tot, 2, 64);
    if (qq == 0) ndrow[kk] = 1.0f / (fabsf(sdegA - (tot + 1.0f)) + 1.0f);
  }
  __syncthreads();     // breg reads of SH done; SH free for X staging

  //======== MPM: point-to-point, tag-embedded publish, NO flags/drains ========
  const int cnt = s_cnt;
  int E_own = 0;

  // ---- iteration 1: X(0) = 1/96 uniform, no staging needed ----
  {
    float vm = 0.0f;
    #pragma unroll
    for (int s = 0; s < 24; ++s) vm = fmaxf(vm, breg[s] * (1.0f/96.0f));
    vm = fmaxf(vm, __shfl_xor(vm, 1, 64));
    vm = fmaxf(vm, __shfl_xor(vm, 2, 64));
    float acc = 0.0f;
    for (int n = 0; n < cnt; ++n) acc += vm;  // ascending-j, identical terms
    if (qq == 0) xb2[kk] = (1.0f/96.0f) * ndrow[kk] + acc;
  }
  __syncthreads();
  if (t < 64) {
    float m = xb2[t];
    if (t < 32) m = fmaxf(m, xb2[64 + t]);
    m = wmax(m);
    if (t == 0) s_ei = ilogbf(m);
  }
  __syncthreads();
  E_own += s_ei;
  {
    const ull tagw = (ep64 + 1ull) << 32;
    if (qq == 0) {
      float Pv = ldexpf(xb2[kk], -s_ei);
      xb2[kk] = Pv;
      stp(&d_Pw[1][b*NN + kk].x, tagw | (ull)(unsigned)E_own);
      stp(&d_Pw[1][b*NN + kk].y, tagw | (ull)__float_as_uint(Pv));
    }
  }

  // ---- iterations 2..50 ----
  for (int it = 2; it <= ITERS; ++it) {
    const int pb = (it - 1) & 1;
    const ull want = ep64 + (ull)(it - 1);
    const int lim = cnt * NN;
    ull wa[8], wb[8];
    // load tagged pairs directly; retry until block-wide valid (single-trip sync)
    for (;;) {
      #pragma unroll
      for (int r = 0; r < 8; ++r) {
        int idx = t + r*NTHR;
        if (idx < lim) {
          int slot = idx / NN, col = idx - slot*NN;
          const ulonglong2* wp = &d_Pw[pb][nbrL[slot]*NN + col];
          wa[r] = ldp(&wp->x);
          wb[r] = ldp(&wp->y);
        }
      }
      int ok = 1;
      #pragma unroll
      for (int r = 0; r < 8; ++r) {
        int idx = t + r*NTHR;
        if (idx < lim) ok &= ((wa[r] >> 32) == want) && ((wb[r] >> 32) == want);
      }
      if (__syncthreads_and(ok)) break;
      __builtin_amdgcn_s_sleep(1);
    }
    #pragma unroll
    for (int r = 0; r < 8; ++r) {
      int idx = t + r*NTHR;
      if (idx < lim) {
        int Ej = (int)(unsigned)(wa[r] & 0xFFFFFFFFull);
        float v = __uint_as_float((unsigned)(wb[r] & 0xFFFFFFFFull));
        SH[idx] = ldexpf(v, Ej - E_own);      // exact pow2 rescale to b-units
      }
    }
    for (int idx = t + 8*NTHR; idx < lim; idx += NTHR) {   // deg>32 fallback
      int slot = idx / NN, col = idx - slot*NN;
      const ulonglong2* wp = &d_Pw[pb][nbrL[slot]*NN + col];
      ull A, B;
      do {
        A = ldp(&wp->x); B = ldp(&wp->y);
        if (((A >> 32) == want) && ((B >> 32) == want)) break;
        __builtin_amdgcn_s_sleep(1);
      } while (true);
      SH[idx] = ldexpf(__uint_as_float((unsigned)(B & 0xFFFFFFFFull)),
                       (int)(unsigned)(A & 0xFFFFFFFFull) - E_own);
    }
    __syncthreads();
    // compute own row (ascending-j order = reference order)
    float acc = 0.0f;
    for (int n = 0; n < cnt; ++n) {
      const float4* xp = reinterpret_cast<const float4*>(&SH[n*NN + qq*24]);
      float vm = 0.0f;
      #pragma unroll
      for (int s6 = 0; s6 < 6; ++s6) {
        float4 xv = xp[s6];
        vm = fmaxf(vm, breg[4*s6+0] * xv.x);
        vm = fmaxf(vm, breg[4*s6+1] * xv.y);
        vm = fmaxf(vm, breg[4*s6+2] * xv.z);
        vm = fmaxf(vm, breg[4*s6+3] * xv.w);
      }
      vm = fmaxf(vm, __shfl_xor(vm, 1, 64));
      vm = fmaxf(vm, __shfl_xor(vm, 2, 64));
      acc += vm;
    }
    if (qq == 0) xb2[kk] = xb2[kk] * ndrow[kk] + acc;   // own term in b-units
    __syncthreads();
    // pow2 renormalize and publish tagged
    if (t < 64) {
      float m = xb2[t];
      if (t < 32) m = fmaxf(m, xb2[64 + t]);
      m = wmax(m);
      if (t == 0) s_ei = ilogbf(m);
    }
    __syncthreads();
    E_own += s_ei;
    {
      const ull tagw = (ep64 + (ull)it) << 32;
      if (qq == 0) {
        float Pv = ldexpf(xb2[kk], -s_ei);
        xb2[kk] = Pv;
        stp(&d_Pw[it & 1][b*NN + kk].x, tagw | (ull)(unsigned)E_own);
        stp(&d_Pw[it & 1][b*NN + kk].y, tagw | (ull)__float_as_uint(Pv));
      }
    }
  }

  //======== final: publish row ssq; one global barrier; exponent-aware normalize ========
  if (t < NN) rowsq[t] = xb2[t] * xb2[t];
  __syncthreads();
  if (t < 64) {
    float v = rowsq[t] + ((t < 32) ? rowsq[64 + t] : 0.0f);
    v = wsum(v);
    if (t == 0) gst(&d_rssq[b], v);
  }
  gbar(7, base);
  // every block reads all 96 (ssq_j, E_j); identical order -> identical result
  if (t < NN) {
    ull A = ldp(&d_Pw[ITERS & 1][t*NN].x);    // E_j rides in word A of elem 0
    s_dE[t] = (int)(unsigned)(A & 0xFFFFFFFFull);
    rowsq[t] = gld(&d_rssq[t]);
  }
  __syncthreads();
  if (t == 0) {
    int em = s_dE[0];
    for (int j = 1; j < NN; ++j) em = max(em, s_dE[j]);
    float s = 0.0f;
    for (int j = 0; j < NN; ++j) s += ldexpf(rowsq[j], 2*(s_dE[j] - em));
    s_emax = em;
    sF = 1.0f / sqrtf(s);
  }
  __syncthreads();
  if (t < NN) p.out[b*NN + t] = ldexpf(xb2[t] * sF, E_own - s_emax);

  if (b == 0 && t == 0)
    __hip_atomic_fetch_add(&d_epoch, 1, __ATOMIC_RELAXED, __HIP_MEMORY_SCOPE_AGENT);
}

extern "C" void kernel_launch(void* const* d_in, const int* in_sizes, int n_in,
                              void* d_out, int out_size, void* d_ws, size_t ws_size,
                              hipStream_t stream) {
  Params prm;
  prm.x   = (const float*)d_in[0];
  prm.ei  = (const int*  )d_in[1];
  prm.adj = (const float*)d_in[2];
  prm.W1  = (const float*)d_in[3];
  prm.b1  = (const float*)d_in[4];
  prm.g1  = (const float*)d_in[5];
  prm.be1 = (const float*)d_in[6];
  prm.W2  = (const float*)d_in[7];
  prm.b2  = (const float*)d_in[8];
  prm.g2  = (const float*)d_in[9];
  prm.be2 = (const float*)d_in[10];
  prm.Wmu = (const float*)d_in[11];
  prm.bmu = (const float*)d_in[12];
  prm.Wlv = (const float*)d_in[13];
  prm.blv = (const float*)d_in[14];
  prm.Wd1 = (const float*)d_in[15];
  prm.bd1 = (const float*)d_in[16];
  prm.Wd2 = (const float*)d_in[17];
  prm.bd2 = (const float*)d_in[18];
  prm.eps = (const float*)d_in[19];
  prm.out = (float*)d_out;

  // Regular launch: all sync is custom flag-based; 96 blocks <= 256 CUs are
  // co-resident.
  gvae_kernel<<<dim3(NBLK), dim3(NTHR), 0, stream>>>(prm);
}